// Round 2
// baseline (334.400 us; speedup 1.0000x reference)
//
#include <hip/hip_runtime.h>
#include <hip/hip_bf16.h>
#include <cstdint>

// SelfSimilarity: out[b,i,j] = softmax_j( -T * max(||x_i - x_j||^2, 0) )
// bf16 MFMA via norm expansion; ||x||^2 computed from ROUNDED bf16 values so
// the diagonal logit is exactly 0 => max logit is 0 => no online max needed.
//
// V3: two-sweep recompute. V0/V2 kept all 128 P values in registers
// (VGPR ~200+, 2 waves/SIMD) and stored them in a pure burst after the
// sweep — stores never overlapped compute, and occupancy was too thin to
// hide L2 latency. Compute here is trivially cheap (MFMA 4 us, exp2 2 us),
// so we recompute instead of storing P:
//   sweep 1: dots -> exp2 -> row sums only (no P array, ~70 live VGPRs)
//   reduce:  cross-lane/wave sums -> inv (one barrier pair)
//   sweep 2: recompute dots/exp2 (B panel L2-hot), scale, store per tile
// Stores now interleave with MFMA/VALU through the whole second sweep, and
// __launch_bounds__(256,4) gives 4 waves/SIMD with the full grid resident.

using bf16x8 = __attribute__((ext_vector_type(8))) short;
using f32x4  = __attribute__((ext_vector_type(4))) float;

#define TEMP   (1.0f / 13.544f)
#define LOG2E  1.4426950408889634f

// ---------------------------------------------------------------------------
// prep: fp32 -> bf16 (RNE) in MFMA-staging layout + csq[row] = -T*log2e*||x_bf||^2
// ws bf16 layout: [b][group=row>>4][qblock=k>>3][r=row&15][8 elems]
//   -> uint4 index: (b*128+g)*256 + q*16 + r
// ---------------------------------------------------------------------------
__global__ __launch_bounds__(256) void prep_kernel(
    const float* __restrict__ x, uint4* __restrict__ xbf, float* __restrict__ csq)
{
    const int t   = threadIdx.x;
    const int lr  = t >> 4;            // local row 0..15
    const int q   = t & 15;            // k-block of 8
    const int row = blockIdx.x * 16 + lr;   // 0..16383

    const float* xp = x + (size_t)row * 128 + q * 8;
    float4 a0 = *(const float4*)(xp);
    float4 a1 = *(const float4*)(xp + 4);
    float v[8] = {a0.x, a0.y, a0.z, a0.w, a1.x, a1.y, a1.z, a1.w};

    unsigned u[8];
    float s = 0.f;
#pragma unroll
    for (int e = 0; e < 8; ++e) {
        unsigned ui = __float_as_uint(v[e]);
        unsigned r  = (ui + 0x7FFFu + ((ui >> 16) & 1u)) >> 16;   // RNE to bf16
        u[e] = r;
        float d = __uint_as_float(r << 16);                        // decoded value
        s += d * d;                                                // norm of ROUNDED vec
    }
    uint4 pack;
    pack.x = u[0] | (u[1] << 16);
    pack.y = u[2] | (u[3] << 16);
    pack.z = u[4] | (u[5] << 16);
    pack.w = u[6] | (u[7] << 16);

    const int b  = row >> 11;
    const int g  = (row >> 4) & 127;
    const int rr = row & 15;
    xbf[(b * 128 + g) * 256 + q * 16 + rr] = pack;

#pragma unroll
    for (int m = 1; m < 16; m <<= 1) s += __shfl_xor(s, m, 64);
    if (q == 0) csq[row] = s * (-TEMP * LOG2E);
}

// ---------------------------------------------------------------------------
// main: per workgroup, M=16 rows x all 2048 cols, two sweeps.
// 4 waves split each 128-col j-tile (wave w -> cols w*32..w*32+31).
// A fragments pinned in registers; B fragments streamed directly from L2
// (no LDS staging, no barriers inside sweeps).
// logit2 = log2e*(-T*dist) = C2L*dot + csq_i + csq_j, clamped <= 0.
// ---------------------------------------------------------------------------
__global__ __launch_bounds__(256, 4) void sim_kernel(
    const uint4* __restrict__ xbf, const float* __restrict__ csq, float* __restrict__ out)
{
    const int blk  = blockIdx.x;
    const int b    = blk >> 7;            // 128 row-tiles per batch
    const int i0   = (blk & 127) * 16;
    const int tid  = threadIdx.x;
    const int w    = tid >> 6;
    const int lane = tid & 63;
    const int quad = lane >> 4;
    const int l15  = lane & 15;

    __shared__ float lsSum[4][16];
    __shared__ __align__(16) float lsInv[16];

    const uint4* xbb  = xbf + (size_t)b * (128 * 256);
    const float* csqb = csq + b * 2048;

    // A fragments: rows i0..i0+15, all K. lane holds row l15, k-block quad per k4.
    bf16x8 afrag[4];
#pragma unroll
    for (int k4 = 0; k4 < 4; ++k4) {
        uint4 vv = xbb[(i0 >> 4) * 256 + (k4 * 4 + quad) * 16 + l15];
        afrag[k4] = __builtin_bit_cast(bf16x8, vv);
    }

    float csqi[4];
    {
        float4 vv = *(const float4*)(csqb + i0 + quad * 4);
        csqi[0] = vv.x; csqi[1] = vv.y; csqi[2] = vv.z; csqi[3] = vv.w;
    }

    const float C2L = 2.0f * TEMP * LOG2E;
    const int   c0  = w * 32;

    // ---- sweep 1: row sums only -------------------------------------------
    float sum_[4] = {};
#pragma unroll
    for (int jt = 0; jt < 16; ++jt) {
        const int j0 = jt * 128;
        const float csqj0 = csqb[j0 + c0 + l15];
        const float csqj1 = csqb[j0 + c0 + 16 + l15];

        const uint4* b0p = xbb + (size_t)(jt * 8 + w * 2 + 0) * 256 + quad * 16 + l15;
        const uint4* b1p = b0p + 256;

        f32x4 acc[2] = {};
#pragma unroll
        for (int k4 = 0; k4 < 4; ++k4) {
            bf16x8 b0 = __builtin_bit_cast(bf16x8, b0p[k4 * 64]);
            bf16x8 b1 = __builtin_bit_cast(bf16x8, b1p[k4 * 64]);
            acc[0] = __builtin_amdgcn_mfma_f32_16x16x32_bf16(afrag[k4], b0, acc[0], 0, 0, 0);
            acc[1] = __builtin_amdgcn_mfma_f32_16x16x32_bf16(afrag[k4], b1, acc[1], 0, 0, 0);
        }

#pragma unroll
        for (int n = 0; n < 2; ++n) {
            const float cj = n ? csqj1 : csqj0;
#pragma unroll
            for (int r = 0; r < 4; ++r) {
                float lg = fminf(fmaf(C2L, acc[n][r], csqi[r] + cj), 0.f);
                sum_[r] += exp2f(lg);
            }
        }
    }

    // ---- reduce sums: 16-lane col groups (bits 0..3), then across waves ----
#pragma unroll
    for (int r = 0; r < 4; ++r) {
        float s = sum_[r];
        s += __shfl_xor(s, 1, 64);
        s += __shfl_xor(s, 2, 64);
        s += __shfl_xor(s, 4, 64);
        s += __shfl_xor(s, 8, 64);
        sum_[r] = s;
    }
    if (l15 == 0) {
#pragma unroll
        for (int r = 0; r < 4; ++r) lsSum[w][quad * 4 + r] = sum_[r];
    }
    __syncthreads();
    if (tid < 16) {
        float tot = lsSum[0][tid] + lsSum[1][tid] + lsSum[2][tid] + lsSum[3][tid];
        lsInv[tid] = 1.0f / tot;
    }
    __syncthreads();

    float inv_[4];
    {
        float4 vv = *(const float4*)(&lsInv[quad * 4]);
        inv_[0] = vv.x; inv_[1] = vv.y; inv_[2] = vv.z; inv_[3] = vv.w;
    }

    // ---- sweep 2: recompute (B panel is L2-hot), scale, store per tile ----
    // stores interleave with MFMA/exp2 across the whole sweep. Per wave
    // store-pair (op, op+16): lanes cover one full 128B line per row.
    float* outrow = out + ((size_t)b * 2048 + i0) * 2048;
#pragma unroll
    for (int jt = 0; jt < 16; ++jt) {
        const int j0 = jt * 128;
        const float csqj0 = csqb[j0 + c0 + l15];
        const float csqj1 = csqb[j0 + c0 + 16 + l15];

        const uint4* b0p = xbb + (size_t)(jt * 8 + w * 2 + 0) * 256 + quad * 16 + l15;
        const uint4* b1p = b0p + 256;

        f32x4 acc[2] = {};
#pragma unroll
        for (int k4 = 0; k4 < 4; ++k4) {
            bf16x8 b0 = __builtin_bit_cast(bf16x8, b0p[k4 * 64]);
            bf16x8 b1 = __builtin_bit_cast(bf16x8, b1p[k4 * 64]);
            acc[0] = __builtin_amdgcn_mfma_f32_16x16x32_bf16(afrag[k4], b0, acc[0], 0, 0, 0);
            acc[1] = __builtin_amdgcn_mfma_f32_16x16x32_bf16(afrag[k4], b1, acc[1], 0, 0, 0);
        }

#pragma unroll
        for (int n = 0; n < 2; ++n) {
            const float cj = n ? csqj1 : csqj0;
#pragma unroll
            for (int r = 0; r < 4; ++r) {
                float lg = fminf(fmaf(C2L, acc[n][r], csqi[r] + cj), 0.f);
                float p  = exp2f(lg) * inv_[r];
                float* op = outrow + (size_t)(quad * 4 + r) * 2048 + j0 + c0 + l15;
                __builtin_nontemporal_store(p, op + (n ? 16 : 0));
            }
        }
    }
}

extern "C" void kernel_launch(void* const* d_in, const int* in_sizes, int n_in,
                              void* d_out, int out_size, void* d_ws, size_t ws_size,
                              hipStream_t stream) {
    const float* x   = (const float*)d_in[0];
    float*       out = (float*)d_out;
    // ws: [0, 4MB) packed bf16 x; [4MB, 4MB+64KB) csq. Needs ~4.26 MB of ws.
    uint4* xbf = (uint4*)d_ws;
    float* csq = (float*)((char*)d_ws + (size_t)4 * 1024 * 1024);

    prep_kernel<<<1024, 256, 0, stream>>>(x, xbf, csq);     // 16384 rows
    sim_kernel<<<1024, 256, 0, stream>>>(xbf, csq, out);    // 8 batches x 128 row-tiles
}

// Round 4
// 242.327 us; speedup vs baseline: 1.3800x; 1.3800x over previous
//
#include <hip/hip_runtime.h>
#include <hip/hip_bf16.h>
#include <cstdint>

// SelfSimilarity: out[b,i,j] = softmax_j( -T * max(||x_i - x_j||^2, 0) )
// bf16 MFMA via norm expansion; ||x||^2 computed from ROUNDED bf16 values so
// the diagonal logit is exactly 0 => max logit is 0 => no online max needed.
//
// V4: fix the store path. V3's counters showed WRITE=381MB for a 134MB
// output (2.8x amplification) + FETCH=149MB (~output size): the scalar
// dword store pattern wrote 4 scattered 64B half-lines per instruction and
// NT eviction flushed lines half-dirty -> RMW + double line-writes. Fix:
// SWAPPED-OPERAND MFMA (mfma(B,A) -> transposed fragment) so each lane
// holds row i0+l15 with 4 consecutive j in regs -> float4 stores; each
// 128B line fully written by 2 adjacent wave instructions. Also pin batch
// to XCD (b = blk&7 under round-robin dispatch) so each XCD's L2 only
// holds its own 512KB B-panel. Two-sweep recompute structure kept (VGPR
// low, stores interleave with compute in sweep 2).
// (V4b: NT stores must go through clang ext_vector pointees, not HIP float4.)

using bf16x8 = __attribute__((ext_vector_type(8))) short;
using f32x4  = __attribute__((ext_vector_type(4))) float;

#define TEMP   (1.0f / 13.544f)
#define LOG2E  1.4426950408889634f

// ---------------------------------------------------------------------------
// prep: fp32 -> bf16 (RNE) in MFMA-staging layout + csq[row] = -T*log2e*||x_bf||^2
// ws bf16 layout: [b][group=row>>4][qblock=k>>3][r=row&15][8 elems]
//   -> uint4 index: (b*128+g)*256 + q*16 + r
// ---------------------------------------------------------------------------
__global__ __launch_bounds__(256) void prep_kernel(
    const float* __restrict__ x, uint4* __restrict__ xbf, float* __restrict__ csq)
{
    const int t   = threadIdx.x;
    const int lr  = t >> 4;            // local row 0..15
    const int q   = t & 15;            // k-block of 8
    const int row = blockIdx.x * 16 + lr;   // 0..16383

    const float* xp = x + (size_t)row * 128 + q * 8;
    float4 a0 = *(const float4*)(xp);
    float4 a1 = *(const float4*)(xp + 4);
    float v[8] = {a0.x, a0.y, a0.z, a0.w, a1.x, a1.y, a1.z, a1.w};

    unsigned u[8];
    float s = 0.f;
#pragma unroll
    for (int e = 0; e < 8; ++e) {
        unsigned ui = __float_as_uint(v[e]);
        unsigned r  = (ui + 0x7FFFu + ((ui >> 16) & 1u)) >> 16;   // RNE to bf16
        u[e] = r;
        float d = __uint_as_float(r << 16);                        // decoded value
        s += d * d;                                                // norm of ROUNDED vec
    }
    uint4 pack;
    pack.x = u[0] | (u[1] << 16);
    pack.y = u[2] | (u[3] << 16);
    pack.z = u[4] | (u[5] << 16);
    pack.w = u[6] | (u[7] << 16);

    const int b  = row >> 11;
    const int g  = (row >> 4) & 127;
    const int rr = row & 15;
    xbf[(b * 128 + g) * 256 + q * 16 + rr] = pack;

#pragma unroll
    for (int m = 1; m < 16; m <<= 1) s += __shfl_xor(s, m, 64);
    if (q == 0) csq[row] = s * (-TEMP * LOG2E);
}

// ---------------------------------------------------------------------------
// main: per workgroup, M=16 rows x all 2048 cols, two sweeps.
// 4 waves split each 128-col j-tile (wave w -> cols w*32..w*32+31).
// Swapped MFMA: acc[n][r] = out[i0 + l15][jt*128 + w*32 + n*16 + quad*4 + r]
// -> lane-local row, 4 consecutive cols per fragment -> float4 stores.
// logit2 = log2e*(-T*dist) = C2L*dot + csq_i + csq_j, clamped <= 0.
// ---------------------------------------------------------------------------
__global__ __launch_bounds__(256, 4) void sim_kernel(
    const uint4* __restrict__ xbf, const float* __restrict__ csq, float* __restrict__ out)
{
    const int blk  = blockIdx.x;
    const int b    = blk & 7;             // batch pinned to XCD (round-robin dispatch)
    const int i0   = (blk >> 3) * 16;     // 128 row-tiles per batch
    const int tid  = threadIdx.x;
    const int w    = tid >> 6;
    const int lane = tid & 63;
    const int quad = lane >> 4;
    const int l15  = lane & 15;

    __shared__ float lsSum[4][16];
    __shared__ __align__(16) float lsInv[16];

    const uint4* xbb  = xbf + (size_t)b * (128 * 256);
    const float* csqb = csq + b * 2048;

    // A fragments (i-rows): lane holds row i0+l15, k-chunk k4*4+quad.
    bf16x8 afrag[4];
#pragma unroll
    for (int k4 = 0; k4 < 4; ++k4) {
        uint4 vv = xbb[(i0 >> 4) * 256 + (k4 * 4 + quad) * 16 + l15];
        afrag[k4] = __builtin_bit_cast(bf16x8, vv);
    }

    const float csqi = csqb[i0 + l15];    // i is lane-local after the swap
    const float C2L  = 2.0f * TEMP * LOG2E;
    const int   c0   = w * 32;

    // ---- sweep 1: row sums only -------------------------------------------
    float sum_ = 0.f;
#pragma unroll
    for (int jt = 0; jt < 16; ++jt) {
        const int j0 = jt * 128;
        float4 cj0 = *(const float4*)(csqb + j0 + c0 + quad * 4);
        float4 cj1 = *(const float4*)(csqb + j0 + c0 + 16 + quad * 4);

        const uint4* b0p = xbb + (size_t)(jt * 8 + w * 2 + 0) * 256 + quad * 16 + l15;
        const uint4* b1p = b0p + 256;

        f32x4 acc[2] = {};
#pragma unroll
        for (int k4 = 0; k4 < 4; ++k4) {
            bf16x8 b0 = __builtin_bit_cast(bf16x8, b0p[k4 * 64]);
            bf16x8 b1 = __builtin_bit_cast(bf16x8, b1p[k4 * 64]);
            // swapped operands: D[j][i] -> lane = i, reg = j
            acc[0] = __builtin_amdgcn_mfma_f32_16x16x32_bf16(b0, afrag[k4], acc[0], 0, 0, 0);
            acc[1] = __builtin_amdgcn_mfma_f32_16x16x32_bf16(b1, afrag[k4], acc[1], 0, 0, 0);
        }

#pragma unroll
        for (int r = 0; r < 4; ++r) {
            float cj0r = (r == 0) ? cj0.x : (r == 1) ? cj0.y : (r == 2) ? cj0.z : cj0.w;
            float cj1r = (r == 0) ? cj1.x : (r == 1) ? cj1.y : (r == 2) ? cj1.z : cj1.w;
            sum_ += exp2f(fminf(fmaf(C2L, acc[0][r], csqi + cj0r), 0.f));
            sum_ += exp2f(fminf(fmaf(C2L, acc[1][r], csqi + cj1r), 0.f));
        }
    }

    // ---- reduce: across quads (lane bits 4,5), then across waves ----------
    sum_ += __shfl_xor(sum_, 16, 64);
    sum_ += __shfl_xor(sum_, 32, 64);
    if (quad == 0) lsSum[w][l15] = sum_;
    __syncthreads();
    if (tid < 16) {
        lsInv[tid] = 1.0f / (lsSum[0][tid] + lsSum[1][tid] + lsSum[2][tid] + lsSum[3][tid]);
    }
    __syncthreads();
    const float inv = lsInv[l15];

    // ---- sweep 2: recompute (B panel L2-hot), scale, float4 NT stores -----
    // per store: 64 lanes x 16B; rows l15 (16 rows), 64B contiguous per row;
    // the n=0/n=1 pair completes each 128B line back-to-back.
    float* orow = out + ((size_t)b * 2048 + i0 + l15) * 2048;
#pragma unroll
    for (int jt = 0; jt < 16; ++jt) {
        const int j0 = jt * 128;
        float4 cj0 = *(const float4*)(csqb + j0 + c0 + quad * 4);
        float4 cj1 = *(const float4*)(csqb + j0 + c0 + 16 + quad * 4);

        const uint4* b0p = xbb + (size_t)(jt * 8 + w * 2 + 0) * 256 + quad * 16 + l15;
        const uint4* b1p = b0p + 256;

        f32x4 acc[2] = {};
#pragma unroll
        for (int k4 = 0; k4 < 4; ++k4) {
            bf16x8 b0 = __builtin_bit_cast(bf16x8, b0p[k4 * 64]);
            bf16x8 b1 = __builtin_bit_cast(bf16x8, b1p[k4 * 64]);
            acc[0] = __builtin_amdgcn_mfma_f32_16x16x32_bf16(b0, afrag[k4], acc[0], 0, 0, 0);
            acc[1] = __builtin_amdgcn_mfma_f32_16x16x32_bf16(b1, afrag[k4], acc[1], 0, 0, 0);
        }

        f32x4 p0, p1;
        p0[0] = exp2f(fminf(fmaf(C2L, acc[0][0], csqi + cj0.x), 0.f)) * inv;
        p0[1] = exp2f(fminf(fmaf(C2L, acc[0][1], csqi + cj0.y), 0.f)) * inv;
        p0[2] = exp2f(fminf(fmaf(C2L, acc[0][2], csqi + cj0.z), 0.f)) * inv;
        p0[3] = exp2f(fminf(fmaf(C2L, acc[0][3], csqi + cj0.w), 0.f)) * inv;
        p1[0] = exp2f(fminf(fmaf(C2L, acc[1][0], csqi + cj1.x), 0.f)) * inv;
        p1[1] = exp2f(fminf(fmaf(C2L, acc[1][1], csqi + cj1.y), 0.f)) * inv;
        p1[2] = exp2f(fminf(fmaf(C2L, acc[1][2], csqi + cj1.z), 0.f)) * inv;
        p1[3] = exp2f(fminf(fmaf(C2L, acc[1][3], csqi + cj1.w), 0.f)) * inv;

        f32x4* op0 = (f32x4*)(orow + j0 + c0 + quad * 4);
        f32x4* op1 = (f32x4*)(orow + j0 + c0 + 16 + quad * 4);
        __builtin_nontemporal_store(p0, op0);
        __builtin_nontemporal_store(p1, op1);
    }
}

extern "C" void kernel_launch(void* const* d_in, const int* in_sizes, int n_in,
                              void* d_out, int out_size, void* d_ws, size_t ws_size,
                              hipStream_t stream) {
    const float* x   = (const float*)d_in[0];
    float*       out = (float*)d_out;
    // ws: [0, 4MB) packed bf16 x; [4MB, 4MB+64KB) csq. Needs ~4.26 MB of ws.
    uint4* xbf = (uint4*)d_ws;
    float* csq = (float*)((char*)d_ws + (size_t)4 * 1024 * 1024);

    prep_kernel<<<1024, 256, 0, stream>>>(x, xbf, csq);     // 16384 rows
    sim_kernel<<<1024, 256, 0, stream>>>(xbf, csq, out);    // 8 batches x 128 row-tiles
}